// Round 4
// baseline (5663.792 us; speedup 1.0000x reference)
//
#include <hip/hip_runtime.h>
#include <hip/hip_bf16.h>

#define HH 500
#define NSEQ 2304
#define NGOALS 256
#define NHYPS 2048
#define LSEQ 128
#define NVOCAB 1000
#define NEG_SLOPE 0.01f
#define AP 80          // A-chunk LDS row pitch (bytes), 16B-aligned
#define HP 80          // h-tile LDS row pitch

typedef __attribute__((ext_vector_type(4)))  float f32x4;
typedef __attribute__((ext_vector_type(16))) float f32x16;
typedef __attribute__((ext_vector_type(8)))  short short8;
typedef __attribute__((ext_vector_type(4)))  unsigned uint4v;

__device__ __forceinline__ float sigm(float x) { return 1.0f / (1.0f + expf(-x)); }

__device__ __forceinline__ void gload_lds16(const void* g, void* l) {
    __builtin_amdgcn_global_load_lds(
        (const __attribute__((address_space(1))) unsigned int*)g,
        (__attribute__((address_space(3))) unsigned int*)l, 16, 0, 0);
}

__device__ __forceinline__ void lgkm_barrier() {
    asm volatile("s_waitcnt lgkmcnt(0)" ::: "memory");
    __builtin_amdgcn_s_barrier();
}

// ---------- split conversions (verified rounds 2-3) ----------
__global__ void split_emb(const float* __restrict__ emb,
                          __hip_bfloat16* __restrict__ Eh, __hip_bfloat16* __restrict__ El)
{
    int idx = blockIdx.x * 256 + threadIdx.x;          // 1024*512
    if (idx >= 1024 * 512) return;
    int k = idx & 511, r = idx >> 9;
    float v = (r < NVOCAB && k < HH) ? emb[r * HH + k] : 0.0f;
    __hip_bfloat16 h = __float2bfloat16(v);
    Eh[idx] = h;
    El[idx] = __float2bfloat16(v - __bfloat162float(h));
}

__global__ void split_wih(const float* __restrict__ Wih,
                          __hip_bfloat16* __restrict__ Wh, __hip_bfloat16* __restrict__ Wl)
{
    int idx = blockIdx.x * 256 + threadIdx.x;          // 2000*512
    if (idx >= 2000 * 512) return;
    int k = idx & 511, r = idx >> 9;
    float v = (k < HH) ? Wih[r * HH + k] : 0.0f;
    __hip_bfloat16 h = __float2bfloat16(v);
    Wh[idx] = h;
    Wl[idx] = __float2bfloat16(v - __bfloat162float(h));
}

// Whh fp32 [2000][500] -> bf16 Wbi[u*4+g][512] interleaved, zero-padded
__global__ void conv_whh_i(const float* __restrict__ Whh, __hip_bfloat16* __restrict__ Wbi)
{
    int idx = blockIdx.x * 256 + threadIdx.x;          // 2048*512
    if (idx >= 2048 * 512) return;
    int k = idx & 511, row = idx >> 9;
    int u = row >> 2, g = row & 3;
    float v = (u < HH && k < HH) ? Whh[(g * HH + u) * HH + k] : 0.0f;
    Wbi[idx] = __float2bfloat16(v);
}

// ---------- T table: T4f[tok][u*4+g] fp32 = emb @ Wih^T + bih + bhh, split-bf16 ----------
__global__ __launch_bounds__(256) void tgemm_split(
    const __hip_bfloat16* __restrict__ Eh, const __hip_bfloat16* __restrict__ El,
    const __hip_bfloat16* __restrict__ Wh, const __hip_bfloat16* __restrict__ Wl,
    const float* __restrict__ bih, const float* __restrict__ bhh,
    float* __restrict__ T4f)
{
    __shared__ char lds[40960];   // dbuf x {Ah 8K, Al 8K, Bh 2K, Bl 2K}
    int tid = threadIdx.x, w = tid >> 6, lane = tid & 63;
    int j0 = blockIdx.x * 16;     // output col tile (gate-major j)
    int m0 = blockIdx.y * 64;     // emb-row tile
    int lrow = lane >> 3, cblk = (lane & 7) ^ lrow, r7 = lane & 7;
    const short* eh = (const short*)Eh; const short* el = (const short*)El;
    const short* wh = (const short*)Wh; const short* wl = (const short*)Wl;
    f32x4 acc = {};
    int arow = w * 16 + (lane & 15);

    auto STAGE = [&](int buf, int k0) {
        char* base = lds + buf * 20480;
        #pragma unroll
        for (int i = 0; i < 2; ++i) {
            int r = (w * 2 + i) * 8 + lrow;
            gload_lds16(eh + (size_t)(m0 + r) * 512 + k0 + cblk * 8, base + (w * 2 + i) * 1024);
            gload_lds16(el + (size_t)(m0 + r) * 512 + k0 + cblk * 8, base + 8192 + (w * 2 + i) * 1024);
        }
        {
            int half = w & 1;
            int r = half * 8 + lrow;
            const short* src = (w < 2) ? wh : wl;
            int off = (w < 2) ? 16384 : 18432;
            gload_lds16(src + (size_t)(j0 + r) * 512 + cblk * 8 + k0, base + off + half * 1024);
        }
    };

    STAGE(0, 0);
    __syncthreads();
    int cur = 0;
    for (int ch = 0; ch < 8; ++ch) {
        if (ch < 7) STAGE(cur ^ 1, (ch + 1) * 64);
        char* base = lds + cur * 20480;
        #pragma unroll
        for (int ks = 0; ks < 2; ++ks) {
            int blk = (ks * 4 + (lane >> 4)) ^ r7;
            short8 ah = *(const short8*)(base + arow * 128 + blk * 16);
            short8 al = *(const short8*)(base + 8192 + arow * 128 + blk * 16);
            short8 bh = *(const short8*)(base + 16384 + (lane & 15) * 128 + blk * 16);
            short8 bl = *(const short8*)(base + 18432 + (lane & 15) * 128 + blk * 16);
            acc = __builtin_amdgcn_mfma_f32_16x16x32_bf16(ah, bh, acc, 0, 0, 0);
            acc = __builtin_amdgcn_mfma_f32_16x16x32_bf16(ah, bl, acc, 0, 0, 0);
            acc = __builtin_amdgcn_mfma_f32_16x16x32_bf16(al, bh, acc, 0, 0, 0);
        }
        if (ch < 7) { __syncthreads(); cur ^= 1; }
    }
    int j = j0 + (lane & 15);
    int g = (j >= 1500) ? 3 : (j >= 1000) ? 2 : (j >= 500) ? 1 : 0;
    int u = j - g * 500;
    float bias = bih[j] + bhh[j];
    #pragma unroll
    for (int r = 0; r < 4; ++r) {
        int m = m0 + w * 16 + (lane >> 4) * 4 + r;
        if (m < NVOCAB) T4f[(size_t)m * 2048 + u * 4 + g] = acc[r] + bias;
    }
}

// ---------- persistent LSTM: 192 blocks = 12 n-groups x 16 u-slices ----------
// Block: 192 rows x 32 u x 4 gates. Whh slice (128 KB) resident in LDS all 128 steps.
// c in registers. h exchanged via agent-scope (coherent) loads/stores + per-group barrier.
__global__ __launch_bounds__(256, 1) void lstm_persist(
    const float* __restrict__ T4f,
    const int* __restrict__ goals, const int* __restrict__ hyps,
    const __hip_bfloat16* __restrict__ Wbi,
    unsigned* __restrict__ hA, unsigned* __restrict__ hB,
    unsigned* __restrict__ barct)
{
    extern __shared__ char smem[];
    char* Bs  = smem;                       // 131072: 128 rows x 1024 B, granule-swizzled
    char* Ab0 = smem + 131072;              // 15360 (192 x 80)
    char* Ab1 = smem + 131072 + 15360;      // 15360
    char* xp  = smem + 131072;              // epilogue transpose: 4 KB per wave (16 KB)
    char* htile = smem + 131072 + 16384;    // 15360
    int* toks = (int*)(smem + 162816);      // 768

    const int tid = threadIdx.x;
    const int lane = tid & 63;
    const int w = tid >> 6;
    const int U = blockIdx.x, G = blockIdx.y;
    const int u0 = U * 32;
    const int rh = w >> 1, uh = w & 1;
    const int l31 = lane & 31;

    // ---- stage B-slice once (swizzled source -> linear LDS => swizzled layout) ----
    {
        const short* wbs = (const short*)Wbi;
        for (int i = 0; i < 32; ++i) {
            int r = w * 32 + i;   // 0..127
            gload_lds16(wbs + (size_t)(u0 * 4 + r) * 512 + (size_t)((lane ^ (r & 7)) * 8),
                        Bs + r * 1024);
        }
    }
    __syncthreads();

    float cst[24];
    #pragma unroll
    for (int i = 0; i < 24; ++i) cst[i] = 0.f;

    for (int t = 0; t < LSEQ; ++t) {
        const unsigned* hR = (t & 1) ? hB : hA;
        unsigned* hW = (t & 1) ? hA : hB;

        if (tid < 192) {
            int n = G * 192 + tid;
            toks[tid] = (n < NGOALS) ? goals[n * LSEQ + t] : hyps[(n - NGOALS) * LSEQ + t];
        }

        // prefetch sets (2-deep pipeline), 12 u32 each
        unsigned pf0[12], pf1[12];
        #pragma unroll
        for (int p = 0; p < 3; ++p) {
            int gidx = p * 256 + tid;
            int row = gidx >> 2, q = gidx & 3;
            const unsigned* gp = hR + (size_t)(G * 192 + row) * 256 + q * 4;
            #pragma unroll
            for (int e = 0; e < 4; ++e) {
                pf0[p*4+e] = __hip_atomic_load((unsigned*)(gp + e),      __ATOMIC_RELAXED, __HIP_MEMORY_SCOPE_AGENT);
                pf1[p*4+e] = __hip_atomic_load((unsigned*)(gp + 16 + e), __ATOMIC_RELAXED, __HIP_MEMORY_SCOPE_AGENT);
            }
        }
        // write ch0, refill set0 <- ch2
        #pragma unroll
        for (int p = 0; p < 3; ++p) {
            int gidx = p * 256 + tid;
            int row = gidx >> 2, q = gidx & 3;
            int qs = q ^ (row & 3) ^ ((row >> 3) & 3);
            *(uint4v*)(Ab0 + row * AP + qs * 16) = *(uint4v*)&pf0[p*4];
        }
        #pragma unroll
        for (int p = 0; p < 3; ++p) {
            int gidx = p * 256 + tid;
            int row = gidx >> 2, q = gidx & 3;
            const unsigned* gp = hR + (size_t)(G * 192 + row) * 256 + 2 * 16 + q * 4;
            #pragma unroll
            for (int e = 0; e < 4; ++e)
                pf0[p*4+e] = __hip_atomic_load((unsigned*)(gp + e), __ATOMIC_RELAXED, __HIP_MEMORY_SCOPE_AGENT);
        }
        lgkm_barrier();

        // T4 prefetch (fp32, interleaved [tok][u*4+g]) — hides under chunk loop
        f32x4 t4r[3][4][2];
        #pragma unroll
        for (int rb = 0; rb < 3; ++rb)
        #pragma unroll
        for (int s = 0; s < 4; ++s) {
            int rowblk = rh * 96 + rb * 32 + (lane >> 3) + 8 * s;
            int tok = toks[rowblk];
            const float* tp = T4f + (size_t)tok * 2048 + (size_t)(u0 + uh * 16 + (lane & 7)) * 4;
            t4r[rb][s][0] = *(const f32x4*)(tp);
            t4r[rb][s][1] = *(const f32x4*)(tp + 32);
        }

        f32x16 acc[3][2] = {};

        #pragma unroll
        for (int ch = 0; ch < 16; ++ch) {
            char* A_ = (ch & 1) ? Ab1 : Ab0;
            #pragma unroll
            for (int s = 0; s < 2; ++s) {
                short8 bfr[2];
                #pragma unroll
                for (int f = 0; f < 2; ++f) {
                    int RB = uh * 64 + f * 32 + l31;
                    int gl = (ch * 4 + s * 2 + (lane >> 5)) ^ (RB & 7);
                    bfr[f] = *(const short8*)(Bs + RB * 1024 + gl * 16);
                }
                #pragma unroll
                for (int rb = 0; rb < 3; ++rb) {
                    int rA = rh * 96 + rb * 32 + l31;
                    int q = s * 2 + (lane >> 5);
                    int qs = q ^ (rA & 3) ^ ((rA >> 3) & 3);
                    short8 a = *(const short8*)(A_ + rA * AP + qs * 16);
                    acc[rb][0] = __builtin_amdgcn_mfma_f32_32x32x16_bf16(a, bfr[0], acc[rb][0], 0, 0, 0);
                    acc[rb][1] = __builtin_amdgcn_mfma_f32_32x32x16_bf16(a, bfr[1], acc[rb][1], 0, 0, 0);
                }
            }
            if (ch < 15) {
                char* W_ = ((ch + 1) & 1) ? Ab1 : Ab0;
                #pragma unroll
                for (int p = 0; p < 3; ++p) {
                    int gidx = p * 256 + tid;
                    int row = gidx >> 2, q = gidx & 3;
                    int qs = q ^ (row & 3) ^ ((row >> 3) & 3);
                    if ((ch + 1) & 1) *(uint4v*)(W_ + row * AP + qs * 16) = *(uint4v*)&pf1[p*4];
                    else              *(uint4v*)(W_ + row * AP + qs * 16) = *(uint4v*)&pf0[p*4];
                }
                if (ch + 3 <= 15) {
                    #pragma unroll
                    for (int p = 0; p < 3; ++p) {
                        int gidx = p * 256 + tid;
                        int row = gidx >> 2, q = gidx & 3;
                        const unsigned* gp = hR + (size_t)(G * 192 + row) * 256 + (ch + 3) * 16 + q * 4;
                        #pragma unroll
                        for (int e = 0; e < 4; ++e) {
                            unsigned v = __hip_atomic_load((unsigned*)(gp + e), __ATOMIC_RELAXED, __HIP_MEMORY_SCOPE_AGENT);
                            if ((ch + 1) & 1) pf1[p*4+e] = v; else pf0[p*4+e] = v;
                        }
                    }
                }
            }
            lgkm_barrier();
        }

        // ---- epilogue: LDS gate-transpose + pointwise, c in regs ----
        char* xw = xp + w * 4096;
        int ul = l31 >> 2, gg = l31 & 3;
        #pragma unroll
        for (int rb = 0; rb < 3; ++rb)
        #pragma unroll
        for (int f = 0; f < 2; ++f) {
            #pragma unroll
            for (int reg = 0; reg < 16; ++reg) {
                int row = (reg & 3) + 8 * (reg >> 2) + 4 * (lane >> 5);
                *(float*)(xw + row * 128 + ul * 16 + gg * 4) = acc[rb][f][reg];
            }
            __threadfence_block();
            #pragma unroll
            for (int s = 0; s < 4; ++s) {
                int row = s * 8 + (lane >> 3), ulr = lane & 7;
                f32x4 gv = *(const f32x4*)(xw + row * 128 + ulr * 16);
                f32x4 tv = t4r[rb][s][f];
                float gi = gv[0] + tv[0];
                float gf = gv[1] + tv[1];
                float gt = gv[2] + tv[2];
                float go = gv[3] + tv[3];
                float si = sigm(gi), sf = sigm(gf), so = sigm(go);
                int ci = (rb * 2 + f) * 4 + s;
                float cv = sf * cst[ci] + si * tanhf(gt);
                cst[ci] = cv;
                float hv = so * tanhf(cv);
                int rowblk = rh * 96 + rb * 32 + row;
                int ull = uh * 16 + f * 8 + ulr;
                *(__hip_bfloat16*)(htile + rowblk * HP + ull * 2) = __float2bfloat16(hv);
            }
            __threadfence_block();
        }
        lgkm_barrier();

        // cooperative coherent h-store (u32 = 2 bf16)
        #pragma unroll
        for (int p = 0; p < 12; ++p) {
            int row = p * 16 + (tid >> 4);
            int wd = tid & 15;
            unsigned v = *(const unsigned*)(htile + row * HP + wd * 4);
            __hip_atomic_store(hW + (size_t)(G * 192 + row) * 256 + (size_t)(u0 >> 1) + wd,
                               v, __ATOMIC_RELAXED, __HIP_MEMORY_SCOPE_AGENT);
        }

        if (t < LSEQ - 1) {
            __threadfence();     // drain coherent stores to LLC
            __syncthreads();
            if (tid == 0) {
                unsigned* ctr = barct + (G * LSEQ + t);
                __hip_atomic_fetch_add(ctr, 1u, __ATOMIC_RELAXED, __HIP_MEMORY_SCOPE_AGENT);
                while (__hip_atomic_load(ctr, __ATOMIC_RELAXED, __HIP_MEMORY_SCOPE_AGENT) < 16u)
                    __builtin_amdgcn_s_sleep(8);
            }
            __syncthreads();
        }
    }
}

// ---------- fused tail: segsum + concat + 3 layers + rownorm; 1 block per output row ----------
__global__ __launch_bounds__(256) void tail_fused(
    const __hip_bfloat16* __restrict__ hfin, const int* __restrict__ segid,
    const float* __restrict__ W1, const float* __restrict__ b1,
    const float* __restrict__ W2, const float* __restrict__ b2,
    const float* __restrict__ Wf, const float* __restrict__ bf,
    float* __restrict__ out)
{
    __shared__ float x[1008];
    __shared__ float y[504];
    __shared__ float z[504];
    __shared__ int lohi[2];
    __shared__ float redw[4];
    __shared__ float rnorm;
    int r = blockIdx.x, tid = threadIdx.x;
    int lane = tid & 63, w = tid >> 6;

    if (tid < 2) {
        int target = r + tid;
        int lo = 0, hi = NHYPS;
        while (lo < hi) { int m = (lo + hi) >> 1; if (segid[m] < target) lo = m + 1; else hi = m; }
        lohi[tid] = lo;
    }
    for (int u = tid; u < HH; u += 256)
        x[u] = __bfloat162float(hfin[(size_t)r * 512 + u]);
    __syncthreads();
    int lo = lohi[0], hi = lohi[1];
    for (int u = tid; u < HH; u += 256) {
        float s = 0.f;
        for (int q = lo; q < hi; ++q)
            s += __bfloat162float(hfin[(size_t)(NGOALS + q) * 512 + u]);
        x[HH + u] = s;
    }
    __syncthreads();
    for (int o = tid; o < HH; o += 256) {
        const float* wr = W1 + (size_t)o * 1000;
        float a = b1[o];
        for (int k = 0; k < 1000; k += 4) {
            f32x4 wv = *(const f32x4*)(wr + k);
            a += wv[0] * x[k] + wv[1] * x[k+1] + wv[2] * x[k+2] + wv[3] * x[k+3];
        }
        y[o] = (a >= 0.f) ? a : NEG_SLOPE * a;
    }
    __syncthreads();
    for (int o = tid; o < HH; o += 256) {
        const float* wr = W2 + (size_t)o * 500;
        float a = b2[o];
        for (int k = 0; k < 500; k += 4) {
            f32x4 wv = *(const f32x4*)(wr + k);
            a += wv[0] * y[k] + wv[1] * y[k+1] + wv[2] * y[k+2] + wv[3] * y[k+3];
        }
        z[o] = (a >= 0.f) ? a : NEG_SLOPE * a;
    }
    __syncthreads();
    for (int o = tid; o < HH; o += 256) {
        const float* wr = Wf + (size_t)o * 500;
        float a = bf[o];
        for (int k = 0; k < 500; k += 4) {
            f32x4 wv = *(const f32x4*)(wr + k);
            a += wv[0] * z[k] + wv[1] * z[k+1] + wv[2] * z[k+2] + wv[3] * z[k+3];
        }
        y[o] = a;
    }
    __syncthreads();
    float p = 0.f;
    for (int u = tid; u < HH; u += 256) p += y[u] * y[u];
    #pragma unroll
    for (int off = 32; off > 0; off >>= 1) p += __shfl_down(p, off);
    if (lane == 0) redw[w] = p;
    __syncthreads();
    if (tid == 0) rnorm = fmaxf(sqrtf(redw[0] + redw[1] + redw[2] + redw[3]), 1e-12f);
    __syncthreads();
    for (int u = tid; u < HH; u += 256) out[(size_t)r * HH + u] = y[u] / rnorm;
}

extern "C" void kernel_launch(void* const* d_in, const int* in_sizes, int n_in,
                              void* d_out, int out_size, void* d_ws, size_t ws_size,
                              hipStream_t stream)
{
    const int*   goals = (const int*)d_in[0];
    const int*   hyps  = (const int*)d_in[1];
    const int*   segid = (const int*)d_in[2];
    const float* emb   = (const float*)d_in[3];
    const float* Wih   = (const float*)d_in[4];
    const float* Whh   = (const float*)d_in[5];
    const float* bih   = (const float*)d_in[6];
    const float* bhh   = (const float*)d_in[7];
    const float* W1    = (const float*)d_in[8];
    const float* b1    = (const float*)d_in[9];
    const float* W2    = (const float*)d_in[10];
    const float* b2    = (const float*)d_in[11];
    const float* Wf    = (const float*)d_in[12];
    const float* bf    = (const float*)d_in[13];
    float* out = (float*)d_out;

    char* base = (char*)d_ws;
    float*          T4f = (float*)(base + 0);                   // 8,192,000
    __hip_bfloat16* Wbi = (__hip_bfloat16*)(base + 8192000);    // 2,097,152
    __hip_bfloat16* hA  = (__hip_bfloat16*)(base + 10289152);   // 2,359,296
    __hip_bfloat16* hB  = (__hip_bfloat16*)(base + 12648448);   // 2,359,296
    unsigned*       barct = (unsigned*)(base + 15007744);       // 6,144
    __hip_bfloat16* Eh  = (__hip_bfloat16*)(base + 15013888);   // 1,048,576
    __hip_bfloat16* El  = (__hip_bfloat16*)(base + 16062464);   // 1,048,576
    __hip_bfloat16* Wh  = (__hip_bfloat16*)(base + 17111040);   // 2,048,000
    __hip_bfloat16* Wl  = (__hip_bfloat16*)(base + 19159040);   // 2,048,000

    split_emb<<<2048, 256, 0, stream>>>(emb, Eh, El);
    split_wih<<<4000, 256, 0, stream>>>(Wih, Wh, Wl);
    conv_whh_i<<<4096, 256, 0, stream>>>(Whh, Wbi);
    hipMemsetAsync(T4f, 0, 8192000, stream);
    tgemm_split<<<dim3(125, 16), 256, 0, stream>>>(Eh, El, Wh, Wl, bih, bhh, T4f);

    hipMemsetAsync(hA, 0, 2359296, stream);
    hipMemsetAsync(hB, 0, 2359296, stream);
    hipMemsetAsync(barct, 0, 6144, stream);

    hipFuncSetAttribute((const void*)lstm_persist,
                        hipFuncAttributeMaxDynamicSharedMemorySize, 163584);
    lstm_persist<<<dim3(16, 12), 256, 163584, stream>>>(
        T4f, goals, hyps, Wbi, (unsigned*)hA, (unsigned*)hB, barct);

    tail_fused<<<NGOALS, 256, 0, stream>>>(hA, segid, W1, b1, W2, b2, Wf, bf, out);
}

// Round 5
// 2984.355 us; speedup vs baseline: 1.8978x; 1.8978x over previous
//
#include <hip/hip_runtime.h>
#include <hip/hip_bf16.h>

#define HH 500
#define NSEQ 2304
#define NGOALS 256
#define NHYPS 2048
#define LSEQ 128
#define NVOCAB 1000
#define NEG_SLOPE 0.01f

typedef __attribute__((ext_vector_type(4)))  float f32x4;
typedef __attribute__((ext_vector_type(16))) float f32x16;
typedef __attribute__((ext_vector_type(8)))  short short8;

__device__ __forceinline__ float sigm(float x) { return 1.0f / (1.0f + expf(-x)); }

__device__ __forceinline__ void gload_lds16(const void* g, void* l) {
    __builtin_amdgcn_global_load_lds(
        (const __attribute__((address_space(1))) unsigned int*)g,
        (__attribute__((address_space(3))) unsigned int*)l, 16, 0, 0);
}

// ---------- split conversions (verified r2-r4) ----------
__global__ void split_emb(const float* __restrict__ emb,
                          __hip_bfloat16* __restrict__ Eh, __hip_bfloat16* __restrict__ El)
{
    int idx = blockIdx.x * 256 + threadIdx.x;          // 1024*512
    if (idx >= 1024 * 512) return;
    int k = idx & 511, r = idx >> 9;
    float v = (r < NVOCAB && k < HH) ? emb[r * HH + k] : 0.0f;
    __hip_bfloat16 h = __float2bfloat16(v);
    Eh[idx] = h;
    El[idx] = __float2bfloat16(v - __bfloat162float(h));
}

__global__ void split_wih(const float* __restrict__ Wih,
                          __hip_bfloat16* __restrict__ Wh, __hip_bfloat16* __restrict__ Wl)
{
    int idx = blockIdx.x * 256 + threadIdx.x;          // 2000*512
    if (idx >= 2000 * 512) return;
    int k = idx & 511, r = idx >> 9;
    float v = (k < HH) ? Wih[r * HH + k] : 0.0f;
    __hip_bfloat16 h = __float2bfloat16(v);
    Wh[idx] = h;
    Wl[idx] = __float2bfloat16(v - __bfloat162float(h));
}

// Whh fp32 [2000][500] -> bf16 Wbi[u*4+g][512] interleaved, zero-padded
__global__ void conv_whh_i(const float* __restrict__ Whh, __hip_bfloat16* __restrict__ Wbi)
{
    int idx = blockIdx.x * 256 + threadIdx.x;          // 2048*512
    if (idx >= 2048 * 512) return;
    int k = idx & 511, row = idx >> 9;
    int u = row >> 2, g = row & 3;
    float v = (u < HH && k < HH) ? Whh[(g * HH + u) * HH + k] : 0.0f;
    Wbi[idx] = __float2bfloat16(v);
}

// ---------- T table: T4f[tok][u*4+g] fp32 = emb @ Wih^T + bih + bhh (split-bf16, verified r4) ----------
__global__ __launch_bounds__(256) void tgemm_split(
    const __hip_bfloat16* __restrict__ Eh, const __hip_bfloat16* __restrict__ El,
    const __hip_bfloat16* __restrict__ Wh, const __hip_bfloat16* __restrict__ Wl,
    const float* __restrict__ bih, const float* __restrict__ bhh,
    float* __restrict__ T4f)
{
    __shared__ char lds[40960];   // dbuf x {Ah 8K, Al 8K, Bh 2K, Bl 2K}
    int tid = threadIdx.x, w = tid >> 6, lane = tid & 63;
    int j0 = blockIdx.x * 16;     // output col tile (gate-major j)
    int m0 = blockIdx.y * 64;     // emb-row tile
    int lrow = lane >> 3, cblk = (lane & 7) ^ lrow, r7 = lane & 7;
    const short* eh = (const short*)Eh; const short* el = (const short*)El;
    const short* wh = (const short*)Wh; const short* wl = (const short*)Wl;
    f32x4 acc = {};
    int arow = w * 16 + (lane & 15);

    auto STAGE = [&](int buf, int k0) {
        char* base = lds + buf * 20480;
        #pragma unroll
        for (int i = 0; i < 2; ++i) {
            int r = (w * 2 + i) * 8 + lrow;
            gload_lds16(eh + (size_t)(m0 + r) * 512 + k0 + cblk * 8, base + (w * 2 + i) * 1024);
            gload_lds16(el + (size_t)(m0 + r) * 512 + k0 + cblk * 8, base + 8192 + (w * 2 + i) * 1024);
        }
        {
            int half = w & 1;
            int r = half * 8 + lrow;
            const short* src = (w < 2) ? wh : wl;
            int off = (w < 2) ? 16384 : 18432;
            gload_lds16(src + (size_t)(j0 + r) * 512 + cblk * 8 + k0, base + off + half * 1024);
        }
    };

    STAGE(0, 0);
    __syncthreads();
    int cur = 0;
    for (int ch = 0; ch < 8; ++ch) {
        if (ch < 7) STAGE(cur ^ 1, (ch + 1) * 64);
        char* base = lds + cur * 20480;
        #pragma unroll
        for (int ks = 0; ks < 2; ++ks) {
            int blk = (ks * 4 + (lane >> 4)) ^ r7;
            short8 ah = *(const short8*)(base + arow * 128 + blk * 16);
            short8 al = *(const short8*)(base + 8192 + arow * 128 + blk * 16);
            short8 bh = *(const short8*)(base + 16384 + (lane & 15) * 128 + blk * 16);
            short8 bl = *(const short8*)(base + 18432 + (lane & 15) * 128 + blk * 16);
            acc = __builtin_amdgcn_mfma_f32_16x16x32_bf16(ah, bh, acc, 0, 0, 0);
            acc = __builtin_amdgcn_mfma_f32_16x16x32_bf16(ah, bl, acc, 0, 0, 0);
            acc = __builtin_amdgcn_mfma_f32_16x16x32_bf16(al, bh, acc, 0, 0, 0);
        }
        if (ch < 7) { __syncthreads(); cur ^= 1; }
    }
    int j = j0 + (lane & 15);
    int g = (j >= 1500) ? 3 : (j >= 1000) ? 2 : (j >= 500) ? 1 : 0;
    int u = j - g * 500;
    float bias = bih[j] + bhh[j];
    #pragma unroll
    for (int r = 0; r < 4; ++r) {
        int m = m0 + w * 16 + (lane >> 4) * 4 + r;
        if (m < NVOCAB) T4f[(size_t)m * 2048 + u * 4 + g] = acc[r] + bias;
    }
}

// ---------- LSTM step: 2 waves/block, block 64n x (32u x 4g), wave 64n x 64gc ----------
// B (Wbi) tile rows contiguous at u0*4. XOR-swizzled LDS (r3-verified pattern).
__global__ __launch_bounds__(128, 2) void lstm_step5(
    const float* __restrict__ T4f,
    const int* __restrict__ goals, const int* __restrict__ hyps,
    const __hip_bfloat16* __restrict__ Wbi,
    const __hip_bfloat16* __restrict__ hin,
    __hip_bfloat16* __restrict__ hout,
    float* __restrict__ c, int tstep)
{
    __shared__ char lds[49152];   // dbuf: 2 x (A 8KB + B 16KB); epilogue reuse: 2 x 16KB transpose
    __shared__ int toks[64];
    const int tid = threadIdx.x, w = tid >> 6, lane = tid & 63;
    const int u0 = blockIdx.x * 32;   // 16 u-slices
    const int n0 = blockIdx.y * 64;   // 36 n-tiles
    const int l7 = lane & 7, lrow = lane >> 3, l31 = lane & 31, hh = lane >> 5;

    if (tid < 64) {
        int n = n0 + tid;
        toks[tid] = (n < NGOALS) ? goals[n * LSEQ + tstep] : hyps[(n - NGOALS) * LSEQ + tstep];
    }

    const short* hs = (const short*)hin;
    const short* wsrc = (const short*)Wbi;

    auto STAGE = [&](int buf, int k0) {
        char* Ab = lds + buf * 24576;
        char* Bb = Ab + 8192;
        #pragma unroll
        for (int i = 0; i < 4; ++i) {
            int j = i * 2 + w;            // 0..7
            int row = j * 8 + lrow;       // 0..63
            int cb = l7 ^ lrow ^ (j & 3);
            gload_lds16(hs + (size_t)(n0 + row) * 512 + k0 + cb * 8, Ab + j * 1024);
        }
        #pragma unroll
        for (int i = 0; i < 8; ++i) {
            int j = i * 2 + w;            // 0..15
            int row = j * 8 + lrow;       // 0..127
            int cb = l7 ^ lrow ^ (j & 3);
            gload_lds16(wsrc + (size_t)(u0 * 4 + row) * 512 + k0 + cb * 8, Bb + j * 1024);
        }
    };

    const int key = l7 ^ ((lane >> 3) & 3);
    f32x16 acc[2][2] = {};

    STAGE(0, 0);
    __syncthreads();
    for (int ch = 0; ch < 8; ++ch) {
        if (ch < 7) STAGE((ch & 1) ^ 1, (ch + 1) * 64);
        char* Ab = lds + (ch & 1) * 24576;
        char* Bb = Ab + 8192;
        #pragma unroll
        for (int ks = 0; ks < 4; ++ks) {
            int sl = (2 * ks + hh) ^ key;
            short8 a0 = *(const short8*)(Ab + l31 * 128 + sl * 16);
            short8 a1 = *(const short8*)(Ab + (32 + l31) * 128 + sl * 16);
            short8 b0 = *(const short8*)(Bb + (w * 64 + l31) * 128 + sl * 16);
            short8 b1 = *(const short8*)(Bb + (w * 64 + 32 + l31) * 128 + sl * 16);
            acc[0][0] = __builtin_amdgcn_mfma_f32_32x32x16_bf16(a0, b0, acc[0][0], 0, 0, 0);
            acc[0][1] = __builtin_amdgcn_mfma_f32_32x32x16_bf16(a0, b1, acc[0][1], 0, 0, 0);
            acc[1][0] = __builtin_amdgcn_mfma_f32_32x32x16_bf16(a1, b0, acc[1][0], 0, 0, 0);
            acc[1][1] = __builtin_amdgcn_mfma_f32_32x32x16_bf16(a1, b1, acc[1][1], 0, 0, 0);
        }
        __syncthreads();
    }

    // ---- epilogue: per-wave LDS transpose (reuse dbuf), then fused pointwise ----
    char* xw = lds + w * 16384;   // 64 rows x 64 cols fp32
    #pragma unroll
    for (int bc = 0; bc < 2; ++bc)
        #pragma unroll
        for (int ar = 0; ar < 2; ++ar)
            #pragma unroll
            for (int reg = 0; reg < 16; ++reg) {
                int row = ar * 32 + (reg & 3) + 8 * (reg >> 2) + 4 * hh;
                *(float*)(xw + row * 256 + (bc * 32 + l31) * 4) = acc[ar][bc][reg];
            }
    asm volatile("s_waitcnt lgkmcnt(0)" ::: "memory");

    int uu = lane & 15;
    int rbase = lane >> 4;            // 0..3
    int u = u0 + w * 16 + uu;         // < 512
    #pragma unroll
    for (int i = 0; i < 16; ++i) {
        int row = rbase + i * 4;      // 0..63
        int n = n0 + row;
        f32x4 g4 = *(const f32x4*)(xw + row * 256 + uu * 16);
        f32x4 t4 = *(const f32x4*)(T4f + (size_t)toks[row] * 2048 + (size_t)u * 4);
        float gi = g4[0] + t4[0], gf = g4[1] + t4[1];
        float gt = g4[2] + t4[2], go = g4[3] + t4[3];
        float si = sigm(gi), sf = sigm(gf), so = sigm(go);
        size_t ci = (size_t)n * 512 + u;
        float cv = sf * c[ci] + si * tanhf(gt);
        c[ci] = cv;
        hout[ci] = __float2bfloat16(so * tanhf(cv));
    }
}

// ---------- fused tail (verified r4): segsum + concat + 3 layers + rownorm ----------
__global__ __launch_bounds__(256) void tail_fused(
    const __hip_bfloat16* __restrict__ hfin, const int* __restrict__ segid,
    const float* __restrict__ W1, const float* __restrict__ b1,
    const float* __restrict__ W2, const float* __restrict__ b2,
    const float* __restrict__ Wf, const float* __restrict__ bf,
    float* __restrict__ out)
{
    __shared__ float x[1008];
    __shared__ float y[504];
    __shared__ float z[504];
    __shared__ int lohi[2];
    __shared__ float redw[4];
    __shared__ float rnorm;
    int r = blockIdx.x, tid = threadIdx.x;
    int lane = tid & 63, w = tid >> 6;

    if (tid < 2) {
        int target = r + tid;
        int lo = 0, hi = NHYPS;
        while (lo < hi) { int m = (lo + hi) >> 1; if (segid[m] < target) lo = m + 1; else hi = m; }
        lohi[tid] = lo;
    }
    for (int u = tid; u < HH; u += 256)
        x[u] = __bfloat162float(hfin[(size_t)r * 512 + u]);
    __syncthreads();
    int lo = lohi[0], hi = lohi[1];
    for (int u = tid; u < HH; u += 256) {
        float s = 0.f;
        for (int q = lo; q < hi; ++q)
            s += __bfloat162float(hfin[(size_t)(NGOALS + q) * 512 + u]);
        x[HH + u] = s;
    }
    __syncthreads();
    for (int o = tid; o < HH; o += 256) {
        const float* wr = W1 + (size_t)o * 1000;
        float a = b1[o];
        for (int k = 0; k < 1000; k += 4) {
            f32x4 wv = *(const f32x4*)(wr + k);
            a += wv[0] * x[k] + wv[1] * x[k+1] + wv[2] * x[k+2] + wv[3] * x[k+3];
        }
        y[o] = (a >= 0.f) ? a : NEG_SLOPE * a;
    }
    __syncthreads();
    for (int o = tid; o < HH; o += 256) {
        const float* wr = W2 + (size_t)o * 500;
        float a = b2[o];
        for (int k = 0; k < 500; k += 4) {
            f32x4 wv = *(const f32x4*)(wr + k);
            a += wv[0] * y[k] + wv[1] * y[k+1] + wv[2] * y[k+2] + wv[3] * y[k+3];
        }
        z[o] = (a >= 0.f) ? a : NEG_SLOPE * a;
    }
    __syncthreads();
    for (int o = tid; o < HH; o += 256) {
        const float* wr = Wf + (size_t)o * 500;
        float a = bf[o];
        for (int k = 0; k < 500; k += 4) {
            f32x4 wv = *(const f32x4*)(wr + k);
            a += wv[0] * z[k] + wv[1] * z[k+1] + wv[2] * z[k+2] + wv[3] * z[k+3];
        }
        y[o] = a;
    }
    __syncthreads();
    float p = 0.f;
    for (int u = tid; u < HH; u += 256) p += y[u] * y[u];
    #pragma unroll
    for (int off = 32; off > 0; off >>= 1) p += __shfl_down(p, off);
    if (lane == 0) redw[w] = p;
    __syncthreads();
    if (tid == 0) rnorm = fmaxf(sqrtf(redw[0] + redw[1] + redw[2] + redw[3]), 1e-12f);
    __syncthreads();
    for (int u = tid; u < HH; u += 256) out[(size_t)r * HH + u] = y[u] / rnorm;
}

extern "C" void kernel_launch(void* const* d_in, const int* in_sizes, int n_in,
                              void* d_out, int out_size, void* d_ws, size_t ws_size,
                              hipStream_t stream)
{
    const int*   goals = (const int*)d_in[0];
    const int*   hyps  = (const int*)d_in[1];
    const int*   segid = (const int*)d_in[2];
    const float* emb   = (const float*)d_in[3];
    const float* Wih   = (const float*)d_in[4];
    const float* Whh   = (const float*)d_in[5];
    const float* bih   = (const float*)d_in[6];
    const float* bhh   = (const float*)d_in[7];
    const float* W1    = (const float*)d_in[8];
    const float* b1    = (const float*)d_in[9];
    const float* W2    = (const float*)d_in[10];
    const float* b2    = (const float*)d_in[11];
    const float* Wf    = (const float*)d_in[12];
    const float* bf    = (const float*)d_in[13];
    float* out = (float*)d_out;

    char* base = (char*)d_ws;
    float*          T4f = (float*)(base + 0);                   // 8,192,000
    __hip_bfloat16* Wbi = (__hip_bfloat16*)(base + 8192000);    // 2,097,152
    __hip_bfloat16* hb0 = (__hip_bfloat16*)(base + 10289152);   // 2,359,296
    __hip_bfloat16* hb1 = (__hip_bfloat16*)(base + 12648448);   // 2,359,296
    float*          c   = (float*)(base + 15007744);            // 4,718,592
    // transient aliases (consumed by tgemm_split before hb/c memsets)
    __hip_bfloat16* Eh = (__hip_bfloat16*)(base + 10289152);    // in hb0, 1,048,576
    __hip_bfloat16* El = (__hip_bfloat16*)(base + 11337728);    // in hb0, 1,048,576
    __hip_bfloat16* Wh = (__hip_bfloat16*)(base + 12648448);    // in hb1, 2,048,000
    __hip_bfloat16* Wl = (__hip_bfloat16*)(base + 15007744);    // in c,   2,048,000

    split_emb<<<2048, 256, 0, stream>>>(emb, Eh, El);
    split_wih<<<4000, 256, 0, stream>>>(Wih, Wh, Wl);
    conv_whh_i<<<4096, 256, 0, stream>>>(Whh, Wbi);
    hipMemsetAsync(T4f, 0, 8192000, stream);
    tgemm_split<<<dim3(125, 16), 256, 0, stream>>>(Eh, El, Wh, Wl, bih, bhh, T4f);

    hipMemsetAsync(hb0, 0, 2359296, stream);
    hipMemsetAsync(hb1, 0, 2359296, stream);
    hipMemsetAsync(c,   0, 4718592, stream);

    __hip_bfloat16* hb[2] = { hb0, hb1 };
    for (int t = 0; t < LSEQ; ++t) {
        lstm_step5<<<dim3(16, 36), 128, 0, stream>>>(
            T4f, goals, hyps, Wbi, hb[t & 1], hb[(t + 1) & 1], c, t);
    }
    __hip_bfloat16* hfin = hb0;   // LSEQ even -> final lands in hb0

    tail_fused<<<NGOALS, 256, 0, stream>>>(hfin, segid, W1, b1, W2, b2, Wf, bf, out);
}